// Round 1
// baseline (449.627 us; speedup 1.0000x reference)
//
#include <hip/hip_runtime.h>
#include <stdint.h>

// LocalMHA on MI355X (gfx950).
// Pipeline: convert(fp32->bf16, W transposed) -> GEMM1 (qkv proj, MFMA bf16)
//           -> RoPE (absolute-position, equivalent to reference windowed angles)
//           -> windowed attention (MFMA bf16, sliding window 129)
//           -> GEMM2 (out proj, MFMA bf16, fp32 store)

typedef __attribute__((ext_vector_type(8))) short bfrag;  // 8 bf16 in 4 VGPRs
typedef __attribute__((ext_vector_type(4))) float f4;

#define MFMA_BF16(a, b, c) __builtin_amdgcn_mfma_f32_16x16x32_bf16((a), (b), (c), 0, 0, 0)

static __device__ __forceinline__ short f2bf(float f) {  // round-to-nearest-even
  unsigned u = __builtin_bit_cast(unsigned, f);
  u = (u + 0x7fffu + ((u >> 16) & 1u)) >> 16;
  return (short)u;
}
static __device__ __forceinline__ float bf2f(short s) {
  unsigned u = ((unsigned)(unsigned short)s) << 16;
  return __builtin_bit_cast(float, u);
}

typedef __attribute__((address_space(3))) unsigned lds_u;
typedef __attribute__((address_space(1))) unsigned gbl_u;

// global -> LDS direct DMA, 16B/lane. LDS dest = wave-uniform base + lane*16,
// so we readfirstlane the per-lane-computed LDS address (lane 0 holds the base).
static __device__ __forceinline__ void gl_lds16(const void* g, const void* lds) {
  unsigned loff = (unsigned)__builtin_amdgcn_readfirstlane((int)(uintptr_t)lds);
  __builtin_amdgcn_global_load_lds((gbl_u*)(uintptr_t)g, (lds_u*)(uintptr_t)loff, 16, 0, 0);
}

// ---------------------------------------------------------------------------
// Kernel 1: dtype conversion + weight transposes.
// x (16384x1024 f32) -> xb bf16 ; W_qkv (1024x3072) -> WqkvT (3072x1024) bf16 ;
// W_out (1024x1024) -> WoutT (1024x1024) bf16.
// ---------------------------------------------------------------------------
__global__ __launch_bounds__(256) void convert_kernel(
    const float* __restrict__ x, const float* __restrict__ wqkv, const float* __restrict__ wout,
    short* __restrict__ xb, short* __restrict__ wqkvT, short* __restrict__ woutT) {
  int idx = blockIdx.x * 256 + threadIdx.x;
  if (idx < 16777216) {
    xb[idx] = f2bf(x[idx]);
  } else if (idx < 16777216 + 3145728) {
    int j = idx - 16777216;
    int kk = j / 3072;
    int nn = j - kk * 3072;
    wqkvT[nn * 1024 + kk] = f2bf(wqkv[j]);
  } else {
    int j = idx - (16777216 + 3145728);
    int kk = j >> 10, nn = j & 1023;
    woutT[nn * 1024 + kk] = f2bf(wout[j]);
  }
}

// ---------------------------------------------------------------------------
// m97-style bf16 GEMM: C[M,N] = A[M,K=1024] * Bt[N,K=1024]^T, 128x128 tile,
// BK=32, 4 waves each owning a 64x64 subtile (4x4 of 16x16x32 MFMA).
// MODE 0: epilogue scatters into q/k/v [B,H,N,64] bf16 (qkv projection).
// MODE 1: plain fp32 C store (output projection).
// ---------------------------------------------------------------------------
template <int MODE>
__global__ __launch_bounds__(256) void gemm_bt(
    const short* __restrict__ A, const short* __restrict__ Bt, float* __restrict__ C,
    short* __restrict__ oq, short* __restrict__ ok, short* __restrict__ ov) {
  __shared__ __align__(16) short Al[128 * 32];
  __shared__ __align__(16) short Bl[128 * 32];
  const int bx = blockIdx.x, by = blockIdx.y;
  const int tid = threadIdx.x, lane = tid & 63, wv = tid >> 6;
  const int wr = wv >> 1, wc = wv & 1;
  const int l15 = lane & 15, quad = lane >> 4;

  const short* Ab = A + (size_t)by * 128 * 1024;
  const short* Bb = Bt + (size_t)bx * 128 * 1024;

  // staging chunks: tile = 512 x 16B chunks; chunk c -> row c>>2, col-offset (c&3)*8
  const int c0 = wv * 128 + lane, c1 = c0 + 64;
  const int ra0 = c0 >> 2, oa0 = (c0 & 3) * 8;
  const int ra1 = c1 >> 2, oa1 = (c1 & 3) * 8;

  f4 acc[4][4];
#pragma unroll
  for (int i = 0; i < 4; ++i)
#pragma unroll
    for (int j = 0; j < 4; ++j) acc[i][j] = (f4)0.f;

  for (int kk = 0; kk < 1024; kk += 32) {
    gl_lds16(Ab + (size_t)ra0 * 1024 + kk + oa0, Al + c0 * 8);
    gl_lds16(Ab + (size_t)ra1 * 1024 + kk + oa1, Al + c1 * 8);
    gl_lds16(Bb + (size_t)ra0 * 1024 + kk + oa0, Bl + c0 * 8);
    gl_lds16(Bb + (size_t)ra1 * 1024 + kk + oa1, Bl + c1 * 8);
    __syncthreads();
    bfrag af[4], bfv[4];
#pragma unroll
    for (int t = 0; t < 4; ++t) af[t] = *(const bfrag*)&Al[(wr * 64 + t * 16 + l15) * 32 + quad * 8];
#pragma unroll
    for (int t = 0; t < 4; ++t) bfv[t] = *(const bfrag*)&Bl[(wc * 64 + t * 16 + l15) * 32 + quad * 8];
#pragma unroll
    for (int i = 0; i < 4; ++i)
#pragma unroll
      for (int j = 0; j < 4; ++j) acc[i][j] = MFMA_BF16(af[i], bfv[j], acc[i][j]);
    __syncthreads();
  }

  // epilogue: C/D layout col=lane&15, row=quad*4+reg
#pragma unroll
  for (int i = 0; i < 4; ++i)
#pragma unroll
    for (int j = 0; j < 4; ++j)
#pragma unroll
      for (int r = 0; r < 4; ++r) {
        int m = by * 128 + wr * 64 + i * 16 + quad * 4 + r;
        int n = bx * 128 + wc * 64 + j * 16 + l15;
        float val = acc[i][j][r];
        if (MODE == 0) {
          int b = m >> 12, p = m & 4095;
          int part = n >> 10, hn = n & 1023;
          size_t dst = ((size_t)(b * 16 + (hn >> 6)) * 4096 + p) * 64 + (hn & 63);
          short* o = (part == 0) ? oq : (part == 1) ? ok : ov;
          o[dst] = f2bf(val);
        } else {
          C[(size_t)m * 1024 + n] = val;
        }
      }
}

// ---------------------------------------------------------------------------
// Kernel 3: RoPE, absolute position angles (equivalent to reference windowed
// angles since only phase differences p_k - p_q enter the dot products).
// q additionally scaled by Dh^-0.5 = 0.125 (commutes with rotation).
// idx < 2^23 -> q ; else -> k. Each thread handles one (row, d<32) pair.
// ---------------------------------------------------------------------------
__global__ __launch_bounds__(256) void rope_kernel(short* __restrict__ qb, short* __restrict__ kb) {
  int idx = blockIdx.x * 256 + threadIdx.x;  // 16777216 total
  int which = idx >> 23;
  int rem = idx & 8388607;
  int row = rem >> 5;  // (b*16+h)*4096 + p
  int d = rem & 31;
  short* arr = which ? kb : qb;
  int p = row & 4095;
  float f = exp2f((float)d * -0.4152410118f);  // 10000^(-d/32)
  float ang = (float)p * f;
  float s = __sinf(ang), c = __cosf(ang);
  size_t base = (size_t)row * 64 + d;
  float a = bf2f(arr[base]), b = bf2f(arr[base + 32]);
  float na = a * c - b * s;
  float nb = b * c + a * s;
  if (!which) { na *= 0.125f; nb *= 0.125f; }
  arr[base] = f2bf(na);
  arr[base + 32] = f2bf(nb);
}

// ---------------------------------------------------------------------------
// Kernel 4: windowed attention. One block (256 thr, 4 waves) per (b,h,w).
// Keys for window w are abs positions [w*128-128, w*128+128). Valid keys for
// query i (window-local): jj in [i, i+128], plus jj>=128 when w==0.
// K staged LDS rows stride 72 (2-way conflicts only); V^T staged LDS stride 264;
// P (softmaxed, bf16) reuses the K region in two 128-col passes (wave-private
// rows -> no extra barriers). All matmuls 16x16x32 bf16 MFMA.
// ---------------------------------------------------------------------------
__global__ __launch_bounds__(256) void attn_kernel(
    const short* __restrict__ qb, const short* __restrict__ kb,
    const short* __restrict__ vb, short* __restrict__ ob) {
  constexpr int KST = 72, VST = 264, PST = 136;
  __shared__ __align__(16) short smem[18432 + 16896];  // 69 KB -> 2 blocks/CU
  short* Ks = smem;          // 256 x KST (36864 B); aliased by P (128 x PST = 34816 B)
  short* Pl = smem;
  short* Vt = smem + 18432;  // 64 x VST (33792 B)

  const int bid = blockIdx.x;
  const int w = bid & 31, bh = bid >> 5;
  const int tid = threadIdx.x, lane = tid & 63, wv = tid >> 6;
  const int l15 = lane & 15, quad = lane >> 4;
  const size_t kvbase = (size_t)bh * (4096 * 64);
  const int pk0 = w * 128 - 128;

  // ---- stage K (row layout) and V^T ----
#pragma unroll
  for (int i = 0; i < 8; ++i) {
    int c = tid + i * 256;  // 2048 x 16B chunks
    int row = c >> 3;       // key index jj 0..255
    int d0 = (c & 7) * 8;
    int pk = pk0 + row;
    if (pk < 0) pk = 0;  // out-of-range keys are masked; clamp to stay in bounds
    const size_t src = kvbase + (size_t)pk * 64 + d0;
    bfrag kvv = *(const bfrag*)(kb + src);
    *(bfrag*)&Ks[row * KST + d0] = kvv;
    bfrag vvv = *(const bfrag*)(vb + src);
#pragma unroll
    for (int j = 0; j < 8; ++j) Vt[(d0 + j) * VST + row] = vvv[j];
  }
  __syncthreads();

  // ---- Q A-frags straight from global (A[m=lane&15][k=quad*8+j]) ----
  const int i0 = wv * 32;  // this wave's 32 query rows
  const short* qbase = qb + kvbase + (size_t)(w * 128) * 64;
  bfrag aq[2][2];
#pragma unroll
  for (int rt = 0; rt < 2; ++rt)
#pragma unroll
    for (int ks = 0; ks < 2; ++ks)
      aq[rt][ks] = *(const bfrag*)(qbase + (size_t)(i0 + rt * 16 + l15) * 64 + ks * 32 + quad * 8);

  // ---- sim = Q K^T : 2 row-tiles x 16 col-tiles ----
  f4 sim[2][16];
#pragma unroll
  for (int rt = 0; rt < 2; ++rt)
#pragma unroll
    for (int ct = 0; ct < 16; ++ct) sim[rt][ct] = (f4)0.f;

#pragma unroll
  for (int ct = 0; ct < 16; ++ct) {
    bfrag bk0 = *(const bfrag*)&Ks[(ct * 16 + l15) * KST + quad * 8];
    bfrag bk1 = *(const bfrag*)&Ks[(ct * 16 + l15) * KST + 32 + quad * 8];
#pragma unroll
    for (int rt = 0; rt < 2; ++rt) {
      sim[rt][ct] = MFMA_BF16(aq[rt][0], bk0, sim[rt][ct]);
      sim[rt][ct] = MFMA_BF16(aq[rt][1], bk1, sim[rt][ct]);
    }
  }
  __syncthreads();  // all K reads done; Ks region free for P

  // ---- masked softmax (rows live across the 16 lanes of each quad) ----
  float linv[2][4];
#pragma unroll
  for (int rt = 0; rt < 2; ++rt)
#pragma unroll
    for (int r = 0; r < 4; ++r) {
      const int iloc = i0 + rt * 16 + quad * 4 + r;
      float mx = -1e30f;
#pragma unroll
      for (int ct = 0; ct < 16; ++ct) {
        int jj = ct * 16 + l15;
        bool valid = (jj >= iloc) && (jj <= iloc + 128) && ((w > 0) || (jj >= 128));
        float sv = valid ? sim[rt][ct][r] : -1e30f;
        sim[rt][ct][r] = sv;
        mx = fmaxf(mx, sv);
      }
#pragma unroll
      for (int off = 1; off < 16; off <<= 1) mx = fmaxf(mx, __shfl_xor(mx, off));
      float sum = 0.f;
#pragma unroll
      for (int ct = 0; ct < 16; ++ct) {
        float pv = __expf(sim[rt][ct][r] - mx);
        sim[rt][ct][r] = pv;
        sum += pv;
      }
#pragma unroll
      for (int off = 1; off < 16; off <<= 1) sum += __shfl_xor(sum, off);
      linv[rt][r] = 1.f / sum;
    }

  // ---- out = P V in two 128-key passes; P rows are wave-private in LDS ----
  f4 oacc[2][4];
#pragma unroll
  for (int rt = 0; rt < 2; ++rt)
#pragma unroll
    for (int ctd = 0; ctd < 4; ++ctd) oacc[rt][ctd] = (f4)0.f;

#pragma unroll
  for (int pass = 0; pass < 2; ++pass) {
#pragma unroll
    for (int rt = 0; rt < 2; ++rt)
#pragma unroll
      for (int ct = 0; ct < 8; ++ct) {
        int ctg = pass * 8 + ct;
#pragma unroll
        for (int r = 0; r < 4; ++r)
          Pl[(i0 + rt * 16 + quad * 4 + r) * PST + ct * 16 + l15] = f2bf(sim[rt][ctg][r]);
      }
    // same-wave DS ordering guarantees write->read visibility; rows disjoint across waves
#pragma unroll
    for (int ks = 0; ks < 4; ++ks) {
      bfrag ap[2];
#pragma unroll
      for (int rt = 0; rt < 2; ++rt)
        ap[rt] = *(const bfrag*)&Pl[(i0 + rt * 16 + l15) * PST + ks * 32 + quad * 8];
#pragma unroll
      for (int ctd = 0; ctd < 4; ++ctd) {
        bfrag bv = *(const bfrag*)&Vt[(ctd * 16 + l15) * VST + pass * 128 + ks * 32 + quad * 8];
#pragma unroll
        for (int rt = 0; rt < 2; ++rt) oacc[rt][ctd] = MFMA_BF16(ap[rt], bv, oacc[rt][ctd]);
      }
    }
  }

  // ---- epilogue: normalize and write [b][p][h*64+d] bf16 ----
  const int b = bh >> 4, h = bh & 15;
  short* obase = ob + ((size_t)b * 4096 + w * 128) * 1024 + h * 64;
#pragma unroll
  for (int rt = 0; rt < 2; ++rt)
#pragma unroll
    for (int ctd = 0; ctd < 4; ++ctd)
#pragma unroll
      for (int r = 0; r < 4; ++r) {
        int i = i0 + rt * 16 + quad * 4 + r;
        int d = ctd * 16 + l15;
        obase[(size_t)i * 1024 + d] = f2bf(oacc[rt][ctd][r] * linv[rt][r]);
      }
}

// ---------------------------------------------------------------------------
extern "C" void kernel_launch(void* const* d_in, const int* in_sizes, int n_in,
                              void* d_out, int out_size, void* d_ws, size_t ws_size,
                              hipStream_t stream) {
  const float* x = (const float*)d_in[0];
  const float* wqkv = (const float*)d_in[1];
  const float* wout = (const float*)d_in[2];
  float* out = (float*)d_out;
  char* ws = (char*)d_ws;

  short* qb = (short*)(ws + 0);            // [4,16,4096,64] bf16  (32 MiB)
  short* kb = (short*)(ws + 33554432);     // same
  short* vb = (short*)(ws + 67108864);     // same
  short* xb = (short*)(ws + 100663296);    // x bf16 [16384,1024]; reused as attn_out
  short* ab = xb;                          // alias: xb dead after GEMM1
  short* wqkvT = (short*)(ws + 134217728); // [3072,1024] bf16
  short* woutT = (short*)(ws + 140509184); // [1024,1024] bf16

  convert_kernel<<<81920, 256, 0, stream>>>(x, wqkv, wout, xb, wqkvT, woutT);
  gemm_bt<0><<<dim3(24, 128), 256, 0, stream>>>(xb, wqkvT, nullptr, qb, kb, vb);
  rope_kernel<<<65536, 256, 0, stream>>>(qb, kb);
  attn_kernel<<<2048, 256, 0, stream>>>(qb, kb, vb, ab);
  gemm_bt<1><<<dim3(8, 128), 256, 0, stream>>>(ab, woutT, out, nullptr, nullptr, nullptr);
}

// Round 2
// 407.533 us; speedup vs baseline: 1.1033x; 1.1033x over previous
//
#include <hip/hip_runtime.h>
#include <stdint.h>

// LocalMHA on MI355X (gfx950).
// Pipeline: convert_x (f32->bf16) + transpose_w (LDS-tiled) ->
//           GEMM1 (qkv proj, MFMA bf16, fused RoPE+scale epilogue) ->
//           windowed attention (MFMA bf16, sliding window 129, no-max softmax) ->
//           GEMM2 (out proj, MFMA bf16, fp32 store)
// RoPE with absolute positions is exactly equivalent to the reference's
// windowed angles: scores depend only on phase differences p_q - p_k.

typedef __attribute__((ext_vector_type(8))) short bfrag;  // 8 bf16 in 4 VGPRs
typedef __attribute__((ext_vector_type(4))) float f4;

#define MFMA_BF16(a, b, c) __builtin_amdgcn_mfma_f32_16x16x32_bf16((a), (b), (c), 0, 0, 0)

static __device__ __forceinline__ short f2bf(float f) {  // round-to-nearest-even
  unsigned u = __builtin_bit_cast(unsigned, f);
  u = (u + 0x7fffu + ((u >> 16) & 1u)) >> 16;
  return (short)u;
}
static __device__ __forceinline__ float bf2f(short s) {
  unsigned u = ((unsigned)(unsigned short)s) << 16;
  return __builtin_bit_cast(float, u);
}

typedef __attribute__((address_space(3))) unsigned lds_u;
typedef __attribute__((address_space(1))) unsigned gbl_u;

// global -> LDS direct DMA, 16B/lane. LDS dest = wave-uniform base + lane*16.
static __device__ __forceinline__ void gl_lds16(const void* g, const void* lds) {
  unsigned loff = (unsigned)__builtin_amdgcn_readfirstlane((int)(uintptr_t)lds);
  __builtin_amdgcn_global_load_lds((gbl_u*)(uintptr_t)g, (lds_u*)(uintptr_t)loff, 16, 0, 0);
}

// ---------------------------------------------------------------------------
// Kernel 1a: x (16384x1024 f32) -> xb bf16, vectorized 8 elems/thread.
// ---------------------------------------------------------------------------
__global__ __launch_bounds__(256) void convert_x(const float* __restrict__ x,
                                                 short* __restrict__ xb) {
  int idx = blockIdx.x * 256 + threadIdx.x;  // 2M threads x 8 elems
  size_t base = (size_t)idx * 8;
  float4 a = *(const float4*)(x + base);
  float4 b = *(const float4*)(x + base + 4);
  bfrag o;
  o[0] = f2bf(a.x); o[1] = f2bf(a.y); o[2] = f2bf(a.z); o[3] = f2bf(a.w);
  o[4] = f2bf(b.x); o[5] = f2bf(b.y); o[6] = f2bf(b.z); o[7] = f2bf(b.w);
  *(bfrag*)(xb + base) = o;
}

// ---------------------------------------------------------------------------
// Kernel 1b: LDS-tiled 64x64 transpose+convert of W_qkv [1024,3072] and
// W_out [1024,1024] into N-major bf16 (coalesced reads AND writes).
// grid (16, 64): y<48 -> wqkv tile, else wout tile (y-48).
// ---------------------------------------------------------------------------
__global__ __launch_bounds__(256) void transpose_w(
    const float* __restrict__ wqkv, const float* __restrict__ wout,
    short* __restrict__ wqkvT, short* __restrict__ woutT) {
  __shared__ short t[64][72];
  const int tid = threadIdx.x;
  const int kt = blockIdx.x, yt = blockIdx.y;
  const float* src; short* dst; int N, nt;
  if (yt < 48) { src = wqkv; dst = wqkvT; N = 3072; nt = yt; }
  else         { src = wout; dst = woutT; N = 1024; nt = yt - 48; }
  const int k0 = kt * 64, n0 = nt * 64;
#pragma unroll
  for (int i = 0; i < 4; ++i) {
    int r = i * 16 + (tid >> 4);  // k-local
    int c = (tid & 15) * 4;       // n-local
    float4 v = *(const float4*)(src + (size_t)(k0 + r) * N + n0 + c);
    t[c + 0][r] = f2bf(v.x);
    t[c + 1][r] = f2bf(v.y);
    t[c + 2][r] = f2bf(v.z);
    t[c + 3][r] = f2bf(v.w);
  }
  __syncthreads();
#pragma unroll
  for (int i = 0; i < 2; ++i) {
    int c = tid + i * 256;
    int n = c >> 3, k8 = (c & 7) * 8;
    *(bfrag*)(dst + (size_t)(n0 + n) * 1024 + k0 + k8) = *(const bfrag*)&t[n][k8];
  }
}

// ---------------------------------------------------------------------------
// m97-style bf16 GEMM: C[M,N] = A[M,1024] * Bt[N,1024]^T, 128x128 tile, BK=32,
// 4 waves each owning a 64x64 subtile (4x4 of 16x16x32 MFMA).
// MODE 0: epilogue applies RoPE (q,k) + 0.125 q-scale, scatters into
//         q/k/v [B,H,N,64] bf16. Each thread holds the (d, d+32) RoPE pair
//         as acc[i][j] / acc[i][j+2] for j in {0,1}.
// MODE 1: plain fp32 C store (output projection).
// ---------------------------------------------------------------------------
template <int MODE>
__global__ __launch_bounds__(256) void gemm_bt(
    const short* __restrict__ A, const short* __restrict__ Bt, float* __restrict__ C,
    short* __restrict__ oq, short* __restrict__ ok, short* __restrict__ ov) {
  __shared__ __align__(16) short Al[128 * 32];
  __shared__ __align__(16) short Bl[128 * 32];
  const int bx = blockIdx.x, by = blockIdx.y;
  const int tid = threadIdx.x, lane = tid & 63, wv = tid >> 6;
  const int wr = wv >> 1, wc = wv & 1;
  const int l15 = lane & 15, quad = lane >> 4;

  const short* Ab = A + (size_t)by * 128 * 1024;
  const short* Bb = Bt + (size_t)bx * 128 * 1024;

  const int c0 = wv * 128 + lane, c1 = c0 + 64;
  const int ra0 = c0 >> 2, oa0 = (c0 & 3) * 8;
  const int ra1 = c1 >> 2, oa1 = (c1 & 3) * 8;

  f4 acc[4][4];
#pragma unroll
  for (int i = 0; i < 4; ++i)
#pragma unroll
    for (int j = 0; j < 4; ++j) acc[i][j] = (f4)0.f;

  for (int kk = 0; kk < 1024; kk += 32) {
    gl_lds16(Ab + (size_t)ra0 * 1024 + kk + oa0, Al + c0 * 8);
    gl_lds16(Ab + (size_t)ra1 * 1024 + kk + oa1, Al + c1 * 8);
    gl_lds16(Bb + (size_t)ra0 * 1024 + kk + oa0, Bl + c0 * 8);
    gl_lds16(Bb + (size_t)ra1 * 1024 + kk + oa1, Bl + c1 * 8);
    __syncthreads();
    bfrag af[4], bfv[4];
#pragma unroll
    for (int t = 0; t < 4; ++t) af[t] = *(const bfrag*)&Al[(wr * 64 + t * 16 + l15) * 32 + quad * 8];
#pragma unroll
    for (int t = 0; t < 4; ++t) bfv[t] = *(const bfrag*)&Bl[(wc * 64 + t * 16 + l15) * 32 + quad * 8];
#pragma unroll
    for (int i = 0; i < 4; ++i)
#pragma unroll
      for (int j = 0; j < 4; ++j) acc[i][j] = MFMA_BF16(af[i], bfv[j], acc[i][j]);
    __syncthreads();
  }

  // epilogue: C/D layout col=lane&15, row=quad*4+reg
  if (MODE == 0) {
    const int n64 = bx * 128 + wc * 64;        // 64-aligned -> one (part, head)
    const int part = n64 >> 10;                // 0=q 1=k 2=v (wave-uniform)
    const int head = (n64 & 1023) >> 6;
    short* o = (part == 0) ? oq : (part == 1) ? ok : ov;
    const float f0 = exp2f((float)l15 * -0.41524101186f);         // 10000^(-d/32)
    const float f1 = exp2f((float)(16 + l15) * -0.41524101186f);
#pragma unroll
    for (int i = 0; i < 4; ++i)
#pragma unroll
      for (int r = 0; r < 4; ++r) {
        const int m = by * 128 + wr * 64 + i * 16 + quad * 4 + r;
        const int b = m >> 12, p = m & 4095;
        short* row = o + ((size_t)(b * 16 + head) * 4096 + p) * 64;
        if (part == 2) {
#pragma unroll
          for (int j = 0; j < 4; ++j) row[j * 16 + l15] = f2bf(acc[i][j][r]);
        } else {
#pragma unroll
          for (int j = 0; j < 2; ++j) {
            float av = acc[i][j][r], bv2 = acc[i][j + 2][r];
            float sn, cs;
            __sincosf((float)p * (j ? f1 : f0), &sn, &cs);
            float ra = av * cs - bv2 * sn;
            float rb = bv2 * cs + av * sn;
            if (part == 0) { ra *= 0.125f; rb *= 0.125f; }
            row[j * 16 + l15] = f2bf(ra);
            row[32 + j * 16 + l15] = f2bf(rb);
          }
        }
      }
  } else {
#pragma unroll
    for (int i = 0; i < 4; ++i)
#pragma unroll
      for (int j = 0; j < 4; ++j)
#pragma unroll
        for (int r = 0; r < 4; ++r) {
          int m = by * 128 + wr * 64 + i * 16 + quad * 4 + r;
          int n = bx * 128 + wc * 64 + j * 16 + l15;
          C[(size_t)m * 1024 + n] = acc[i][j][r];
        }
  }
}

// ---------------------------------------------------------------------------
// Kernel 3: windowed attention. One block (256 thr, 4 waves) per (b,h,w).
// Keys for window w: abs positions [w*128-128, w*128+128). Valid keys for
// query i (window-local): jj in [i, i+128], plus jj>=128 when w==0.
// Softmax without max-subtraction: q pre-scaled by 0.125 -> |sim| << 88.
// ---------------------------------------------------------------------------
__global__ __launch_bounds__(256) void attn_kernel(
    const short* __restrict__ qb, const short* __restrict__ kb,
    const short* __restrict__ vb, short* __restrict__ ob) {
  constexpr int KST = 72, VST = 264, PST = 136;
  __shared__ __align__(16) short smem[18432 + 16896];  // 69 KB -> 2 blocks/CU
  short* Ks = smem;          // 256 x KST; aliased by P (128 x PST)
  short* Pl = smem;
  short* Vt = smem + 18432;  // 64 x VST (V transposed)

  const int bid = blockIdx.x;
  const int w = bid & 31, bh = bid >> 5;
  const int tid = threadIdx.x, lane = tid & 63, wv = tid >> 6;
  const int l15 = lane & 15, quad = lane >> 4;
  const size_t kvbase = (size_t)bh * (4096 * 64);
  const int pk0 = w * 128 - 128;

  // ---- Q A-frags straight from global (issued early to overlap staging) ----
  const int i0 = wv * 32;  // this wave's 32 query rows
  const short* qbase = qb + kvbase + (size_t)(w * 128) * 64;
  bfrag aq[2][2];
#pragma unroll
  for (int rt = 0; rt < 2; ++rt)
#pragma unroll
    for (int ks = 0; ks < 2; ++ks)
      aq[rt][ks] = *(const bfrag*)(qbase + (size_t)(i0 + rt * 16 + l15) * 64 + ks * 32 + quad * 8);

  // ---- stage K (row layout) and V^T ----
#pragma unroll
  for (int i = 0; i < 8; ++i) {
    int c = tid + i * 256;  // 2048 x 16B chunks
    int row = c >> 3;       // key index jj 0..255
    int d0 = (c & 7) * 8;
    int pk = pk0 + row;
    if (pk < 0) pk = 0;  // OOB keys are masked; clamp to stay in bounds
    const size_t src = kvbase + (size_t)pk * 64 + d0;
    bfrag kvv = *(const bfrag*)(kb + src);
    *(bfrag*)&Ks[row * KST + d0] = kvv;
    bfrag vvv = *(const bfrag*)(vb + src);
#pragma unroll
    for (int j = 0; j < 8; ++j) Vt[(d0 + j) * VST + row] = vvv[j];
  }
  __syncthreads();

  // ---- sim = Q K^T : 2 row-tiles x 16 col-tiles ----
  f4 sim[2][16];
#pragma unroll
  for (int rt = 0; rt < 2; ++rt)
#pragma unroll
    for (int ct = 0; ct < 16; ++ct) sim[rt][ct] = (f4)0.f;

#pragma unroll
  for (int ct = 0; ct < 16; ++ct) {
    bfrag bk0 = *(const bfrag*)&Ks[(ct * 16 + l15) * KST + quad * 8];
    bfrag bk1 = *(const bfrag*)&Ks[(ct * 16 + l15) * KST + 32 + quad * 8];
#pragma unroll
    for (int rt = 0; rt < 2; ++rt) {
      sim[rt][ct] = MFMA_BF16(aq[rt][0], bk0, sim[rt][ct]);
      sim[rt][ct] = MFMA_BF16(aq[rt][1], bk1, sim[rt][ct]);
    }
  }
  __syncthreads();  // all K reads done; Ks region free for P

  // ---- masked softmax, no max-subtraction (values bounded; fp32 exp safe) ----
  float linv[2][4];
#pragma unroll
  for (int rt = 0; rt < 2; ++rt)
#pragma unroll
    for (int r = 0; r < 4; ++r) {
      const int iloc = i0 + rt * 16 + quad * 4 + r;
      float sum = 0.f;
#pragma unroll
      for (int ct = 0; ct < 16; ++ct) {
        int jj = ct * 16 + l15;
        bool valid = (jj >= iloc) && (jj <= iloc + 128) && ((w > 0) || (jj >= 128));
        float pv = valid ? __expf(sim[rt][ct][r]) : 0.f;
        sim[rt][ct][r] = pv;
        sum += pv;
      }
#pragma unroll
      for (int off = 1; off < 16; off <<= 1) sum += __shfl_xor(sum, off);
      linv[rt][r] = 1.f / sum;
    }

  // ---- out = P V in two 128-key passes; P rows are wave-private in LDS ----
  f4 oacc[2][4];
#pragma unroll
  for (int rt = 0; rt < 2; ++rt)
#pragma unroll
    for (int ctd = 0; ctd < 4; ++ctd) oacc[rt][ctd] = (f4)0.f;

#pragma unroll
  for (int pass = 0; pass < 2; ++pass) {
#pragma unroll
    for (int rt = 0; rt < 2; ++rt)
#pragma unroll
      for (int ct = 0; ct < 8; ++ct) {
        int ctg = pass * 8 + ct;
#pragma unroll
        for (int r = 0; r < 4; ++r)
          Pl[(i0 + rt * 16 + quad * 4 + r) * PST + ct * 16 + l15] = f2bf(sim[rt][ctg][r]);
      }
    // same-wave DS ordering gives write->read visibility; rows disjoint per wave
#pragma unroll
    for (int ks = 0; ks < 4; ++ks) {
      bfrag ap[2];
#pragma unroll
      for (int rt = 0; rt < 2; ++rt)
        ap[rt] = *(const bfrag*)&Pl[(i0 + rt * 16 + l15) * PST + ks * 32 + quad * 8];
#pragma unroll
      for (int ctd = 0; ctd < 4; ++ctd) {
        bfrag bv = *(const bfrag*)&Vt[(ctd * 16 + l15) * VST + pass * 128 + ks * 32 + quad * 8];
#pragma unroll
        for (int rt = 0; rt < 2; ++rt) oacc[rt][ctd] = MFMA_BF16(ap[rt], bv, oacc[rt][ctd]);
      }
    }
  }

  // ---- epilogue: normalize and write [b][p][h*64+d] bf16 ----
  const int b = bh >> 4, h = bh & 15;
  short* obase = ob + ((size_t)b * 4096 + w * 128) * 1024 + h * 64;
#pragma unroll
  for (int rt = 0; rt < 2; ++rt)
#pragma unroll
    for (int ctd = 0; ctd < 4; ++ctd)
#pragma unroll
      for (int r = 0; r < 4; ++r) {
        int i = i0 + rt * 16 + quad * 4 + r;
        int d = ctd * 16 + l15;
        obase[(size_t)i * 1024 + d] = f2bf(oacc[rt][ctd][r] * linv[rt][r]);
      }
}

// ---------------------------------------------------------------------------
extern "C" void kernel_launch(void* const* d_in, const int* in_sizes, int n_in,
                              void* d_out, int out_size, void* d_ws, size_t ws_size,
                              hipStream_t stream) {
  const float* x = (const float*)d_in[0];
  const float* wqkv = (const float*)d_in[1];
  const float* wout = (const float*)d_in[2];
  float* out = (float*)d_out;
  char* ws = (char*)d_ws;

  short* qb = (short*)(ws + 0);            // [4,16,4096,64] bf16  (32 MiB)
  short* kb = (short*)(ws + 33554432);     // same
  short* vb = (short*)(ws + 67108864);     // same
  short* xb = (short*)(ws + 100663296);    // x bf16 [16384,1024]; reused as attn_out
  short* ab = xb;                          // alias: xb dead after GEMM1
  short* wqkvT = (short*)(ws + 134217728); // [3072,1024] bf16
  short* woutT = (short*)(ws + 140509184); // [1024,1024] bf16

  convert_x<<<8192, 256, 0, stream>>>(x, xb);
  transpose_w<<<dim3(16, 64), 256, 0, stream>>>(wqkv, wout, wqkvT, woutT);
  gemm_bt<0><<<dim3(24, 128), 256, 0, stream>>>(xb, wqkvT, nullptr, qb, kb, vb);
  attn_kernel<<<2048, 256, 0, stream>>>(qb, kb, vb, ab);
  gemm_bt<1><<<dim3(8, 128), 256, 0, stream>>>(ab, woutT, out, nullptr, nullptr, nullptr);
}